// Round 3
// baseline (6664.280 us; speedup 1.0000x reference)
//
#include <hip/hip_runtime.h>
#include <hip/hip_fp16.h>

#define B_ 64
#define T_ 512
#define EMB_ 128
#define HID_ 256
#define MEL_ 80

typedef __attribute__((ext_vector_type(8))) _Float16 half8;
typedef __attribute__((ext_vector_type(4))) float f32x4;
typedef __attribute__((ext_vector_type(4))) unsigned int u32x4;

__device__ __forceinline__ float sigf(float x) {
  x = fminf(fmaxf(x, -30.f), 30.f);
  return 1.f / (1.f + __expf(-x));
}
__device__ __forceinline__ float tanhf_(float x) {
  x = fminf(fmaxf(x, -15.f), 15.f);
  float e = __expf(2.f * x);
  return (e - 1.f) / (e + 1.f);
}

// Pack W=[wih|whh] (per dir 1024x384) into MFMA B-frags with PER-BLOCK K order:
// [ x(0..127) | own-slice h(64) | remote slices in pslice order (192) ].
// Rows permuted to gu-order (wave w owns units w*16.., gates via nt=w+4g).
// Wall[((ds*16+nt)*12+kt)*64 + lane][8]
__global__ void k_pack_wall(const float* __restrict__ wih_f, const float* __restrict__ whh_f,
                            const float* __restrict__ wih_b, const float* __restrict__ whh_b,
                            _Float16* __restrict__ Wall) {
  int tid = blockIdx.x * 256 + threadIdx.x;  // 98304 total
  int lane = tid & 63;
  int r = tid >> 6;
  int kt = r % 12; r /= 12;
  int nt = r % 16; r /= 16;
  int ds = r;  // 0..7
  if (ds >= 8) return;
  int dir = ds >> 2, slice = ds & 3;
  const float* wih = dir ? wih_b : wih_f;
  const float* whh = dir ? whh_b : whh_f;
  int gu = nt * 16 + (lane & 15);
  int g = gu >> 6, u = gu & 63;
  int row = g * 256 + slice * 64 + u;
  int kbase = kt * 32 + (lane >> 4) * 8;
  _Float16* dst = Wall + (size_t)tid * 8;
#pragma unroll
  for (int j = 0; j < 8; ++j) {
    int k = kbase + j;
    float v;
    if (k < EMB_) {
      v = wih[row * EMB_ + k];
    } else if (k < EMB_ + 64) {
      v = whh[row * HID_ + slice * 64 + (k - EMB_)];
    } else {
      int jx = k - (EMB_ + 64);
      int rr = jx >> 6;
      int ps = rr + (rr >= slice ? 1 : 0);
      v = whh[row * HID_ + ps * 64 + (jx & 63)];
    }
    dst[j] = (_Float16)v;
  }
}

__global__ void k_pack_misc(const float* __restrict__ bih_f, const float* __restrict__ bhh_f,
                            const float* __restrict__ bih_b, const float* __restrict__ bhh_b,
                            const float* __restrict__ lin_w, float* __restrict__ bsum,
                            _Float16* __restrict__ linWp) {
  int t = blockIdx.x * 256 + threadIdx.x;
  if (t < 2048) {
    int dir = t >> 10, g = t & 1023;
    bsum[t] = dir ? (bih_b[g] + bhh_b[g]) : (bih_f[g] + bhh_f[g]);
  } else if (t < 2048 + 5120) {
    int u = t - 2048;
    int lane = u & 63;
    int r = u >> 6;
    int kt = r % 16, nt = r / 16;
    int n = nt * 16 + (lane & 15);
    int kbase = kt * 32 + (lane >> 4) * 8;
    _Float16* dst = linWp + (size_t)u * 8;
#pragma unroll
    for (int j = 0; j < 8; ++j) dst[j] = (_Float16)lin_w[n * 512 + kbase + j];
  }
}

__global__ void k_dur(const int* __restrict__ x, const float* __restrict__ embed,
                      const float* __restrict__ dp_w, const float* __restrict__ dp_b,
                      int* __restrict__ dur) {
  int gid = blockIdx.x * 256 + threadIdx.x;
  if (gid >= B_ * T_) return;
  const float* er = embed + (size_t)x[gid] * EMB_;
  float d = 0.f;
  for (int e = 0; e < EMB_; ++e) d += er[e] * dp_w[e];
  d += dp_b[0];
  d = fmaxf(d, 0.f);
  dur[gid] = (int)floorf(d) + 1;
}

__global__ void k_scan(const int* __restrict__ dur, int* __restrict__ cum) {
  __shared__ int s[512];
  int b = blockIdx.x, t = threadIdx.x;
  s[t] = dur[b * 512 + t];
  __syncthreads();
  for (int off = 1; off < 512; off <<= 1) {
    int v = (t >= off) ? s[t - off] : 0;
    __syncthreads();
    s[t] += v;
    __syncthreads();
  }
  cum[b * 512 + t] = s[t];
}

__global__ void k_fill(int* __restrict__ p, int n, int v) {
  int gid = blockIdx.x * 256 + threadIdx.x;
  if (gid < n) p[gid] = v;
}

// sentinel-fill hcat (0xFFFFFFFF = fp16 NaN pair, impossible as real h)
__global__ void k_fill_sent(unsigned int* __restrict__ p, int n4) {
  int gid = blockIdx.x * 256 + threadIdx.x;
  if (gid < n4) ((u32x4*)p)[gid] = u32x4{0xFFFFFFFFu, 0xFFFFFFFFu, 0xFFFFFFFFu, 0xFFFFFFFFu};
}

__global__ void k_scatter(const int* __restrict__ cum, int* __restrict__ idx, int L) {
  int b = blockIdx.x, t = threadIdx.x;
  int c1 = cum[b * 512 + t];
  int c0 = t ? cum[b * 512 + t - 1] : 0;
  for (int p = c0; p < c1; ++p)
    if (p < L) idx[(size_t)b * L + p] = t;
}

__global__ void k_expand(const int* __restrict__ x, const float* __restrict__ embed,
                         const int* __restrict__ idx, _Float16* __restrict__ expb, int L) {
  int gid = blockIdx.x * 256 + threadIdx.x;
  if (gid >= B_ * L * 16) return;
  int ch = gid & 15;
  int rem = gid >> 4;
  int l = rem % L;
  int b = rem / L;
  int ix = idx[(size_t)b * L + l];
  half8 v;
  if (ix < 0) {
#pragma unroll
    for (int j = 0; j < 8; ++j) v[j] = (_Float16)0.f;
  } else {
    const float* er = embed + (size_t)x[b * 512 + ix] * EMB_ + ch * 8;
#pragma unroll
    for (int j = 0; j < 8; ++j) v[j] = (_Float16)er[j];
  }
  *(half8*)(expb + ((size_t)b * L + l) * EMB_ + ch * 8) = v;
}

// 8 blocks = 2 dirs x 4 hidden-slices. Weights resident in regs (AGPR side).
// h exchange = sentinel mailbox in hcat: producers store whole u32 (2 units)
// relaxed/agent; consumers poll 24 u32 words each, retrying sentinel words.
// GEMM split: phase A (x + own h, kt 0..5) overlaps the in-flight poll loads;
// phase B (remote, kt 6..11) after validation. Local Ash K-layout matches the
// per-block packed W: [x | own | remote(pslice order)].
__global__ __launch_bounds__(256, 1) void k_rec(
    const _Float16* __restrict__ expb, const _Float16* __restrict__ Wall,
    const float* __restrict__ bsum, _Float16* __restrict__ hcat, int L) {
  __shared__ __align__(16) _Float16 Ash[64][392];
  int tid = threadIdx.x;
  int ds = blockIdx.x;
  int dir = ds >> 2, slice = ds & 3;
  int w = tid >> 6, lane = tid & 63;
  int c = lane & 15, kg = lane >> 4;
  unsigned int* hcat32 = (unsigned int*)hcat;
  // consumer mapping: thread t polls batch cb, canonical remote u32 idx jbase..jbase+23
  int cb = tid >> 2;
  int jbase = (tid & 3) * 24;
  int s32 = slice * 32;

  for (int i = tid; i < 64 * 392 / 8; i += 256)
    ((half8*)&Ash[0][0])[i] = half8{0, 0, 0, 0, 0, 0, 0, 0};
  float bias[4];
#pragma unroll
  for (int g = 0; g < 4; ++g)
    bias[g] = bsum[dir * 1024 + g * 256 + slice * 64 + w * 16 + c];
  half8 breg[4][12];
#pragma unroll
  for (int g = 0; g < 4; ++g) {
    int nt = w + 4 * g;
#pragma unroll
    for (int kt = 0; kt < 12; ++kt)
      breg[g][kt] = *(const half8*)(Wall + (((size_t)(ds * 16 + nt) * 12 + kt) * 64 + lane) * 8);
  }
  float creg[16];
#pragma unroll
  for (int i = 0; i < 16; ++i) creg[i] = 0.f;
  __syncthreads();
  {  // x_0
    int l0 = dir ? (L - 1) : 0;
#pragma unroll
    for (int r = 0; r < 4; ++r) {
      int f = tid + 256 * r;
      int b = f >> 4, ch = f & 15;
      *(half8*)&Ash[b][ch * 8] = *(const half8*)(expb + ((size_t)b * L + l0) * EMB_ + ch * 8);
    }
  }
  __syncthreads();

  for (int s = 0; s < L; ++s) {
    int l_io = dir ? (L - 1 - s) : s;
    // --- p1: issue poll loads for remote h_{s-1} ---
    unsigned int v[24];
    size_t rbase = 0;
    if (s > 0) {
      int l_prev = dir ? (L - s) : (s - 1);
      rbase = ((size_t)cb * L + l_prev) * 256 + dir * 128;
#pragma unroll
      for (int j = 0; j < 24; ++j) {
        int jj = jbase + j;
        int u32o = jj + (jj >= s32 ? 32 : 0);
        v[j] = __hip_atomic_load(&hcat32[rbase + u32o], __ATOMIC_RELAXED,
                                 __HIP_MEMORY_SCOPE_AGENT);
      }
    }
    // --- p2: GEMM-A (x + own h), acc persists ---
    f32x4 acc[4][4];
#pragma unroll
    for (int m = 0; m < 4; ++m)
#pragma unroll
      for (int g = 0; g < 4; ++g) acc[m][g] = f32x4{0.f, 0.f, 0.f, 0.f};
#pragma unroll
    for (int kt = 0; kt < 6; ++kt) {
      half8 a[4];
#pragma unroll
      for (int m = 0; m < 4; ++m) a[m] = *(const half8*)&Ash[m * 16 + c][kt * 32 + kg * 8];
#pragma unroll
      for (int m = 0; m < 4; ++m)
#pragma unroll
        for (int g = 0; g < 4; ++g)
          acc[m][g] = __builtin_amdgcn_mfma_f32_16x16x32_f16(a[m], breg[g][kt], acc[m][g], 0, 0, 0);
    }
    // --- p3: validate poll; write remote h into Ash ---
    if (s > 0) {
      while (true) {
        unsigned int any = 0;
#pragma unroll
        for (int j = 0; j < 24; ++j) any |= (v[j] == 0xFFFFFFFFu) ? 1u : 0u;
        if (!any) break;
        __builtin_amdgcn_s_sleep(1);
#pragma unroll
        for (int j = 0; j < 24; ++j) {
          if (v[j] == 0xFFFFFFFFu) {
            int jj = jbase + j;
            int u32o = jj + (jj >= s32 ? 32 : 0);
            v[j] = __hip_atomic_load(&hcat32[rbase + u32o], __ATOMIC_RELAXED,
                                     __HIP_MEMORY_SCOPE_AGENT);
          }
        }
      }
#pragma unroll
      for (int j = 0; j < 24; ++j) {
        int jj = jbase + j;
        int u32o = jj + (jj >= s32 ? 32 : 0);
        int ps = u32o >> 5;
        int rr = ps - (ps > slice ? 1 : 0);
        int lc = 96 + rr * 32 + (u32o & 31);  // local u32 col: remote region
        ((unsigned int*)&Ash[cb][0])[lc] = v[j];
      }
    }
    __syncthreads();
    // --- p5: x_{s+1} into Ash (free region) + GEMM-B (remote kts) ---
    if (s + 1 < L) {
      int l1 = dir ? (L - 2 - s) : (s + 1);
#pragma unroll
      for (int r = 0; r < 4; ++r) {
        int f = tid + 256 * r;
        int b = f >> 4, ch = f & 15;
        *(half8*)&Ash[b][ch * 8] = *(const half8*)(expb + ((size_t)b * L + l1) * EMB_ + ch * 8);
      }
    }
#pragma unroll
    for (int kt = 6; kt < 12; ++kt) {
      half8 a[4];
#pragma unroll
      for (int m = 0; m < 4; ++m) a[m] = *(const half8*)&Ash[m * 16 + c][kt * 32 + kg * 8];
#pragma unroll
      for (int m = 0; m < 4; ++m)
#pragma unroll
        for (int g = 0; g < 4; ++g)
          acc[m][g] = __builtin_amdgcn_mfma_f32_16x16x32_f16(a[m], breg[g][kt], acc[m][g], 0, 0, 0);
    }
    // --- p6: cell update ---
    _Float16 hv[16];
#pragma unroll
    for (int m = 0; m < 4; ++m)
#pragma unroll
      for (int i = 0; i < 4; ++i) {
        float iv = acc[m][0][i] + bias[0];
        float fv = acc[m][1][i] + bias[1];
        float gv = acc[m][2][i] + bias[2];
        float ov = acc[m][3][i] + bias[3];
        float cc = sigf(fv) * creg[m * 4 + i] + sigf(iv) * tanhf_(gv);
        float hh = sigf(ov) * tanhf_(cc);
        creg[m * 4 + i] = cc;
        hv[m * 4 + i] = (_Float16)hh;
      }
    // --- p7: publish h_s (u32 mailbox) + own h into Ash ---
#pragma unroll
    for (int m = 0; m < 4; ++m)
#pragma unroll
      for (int i = 0; i < 4; ++i) {
        int idx = m * 4 + i;
        int b = m * 16 + kg * 4 + i;
        Ash[b][EMB_ + w * 16 + c] = hv[idx];  // own region = cols 128..191
        unsigned int mine = (unsigned int)__builtin_bit_cast(unsigned short, hv[idx]);
        unsigned int part = (unsigned int)(unsigned)__shfl_xor((int)mine, 1, 64);
        unsigned int word = (c & 1) ? ((mine << 16) | part) : (mine | (part << 16));
        if (((c & 1) == 0) == (m < 2))
          __hip_atomic_store(
              &hcat32[((size_t)b * L + l_io) * 256 + dir * 128 + slice * 32 + w * 8 + (c >> 1)],
              word, __ATOMIC_RELAXED, __HIP_MEMORY_SCOPE_AGENT);
      }
    __syncthreads();
  }
}

__global__ __launch_bounds__(256) void k_linear(
    const _Float16* __restrict__ hcat, const _Float16* __restrict__ linWp,
    const float* __restrict__ lin_b, float* __restrict__ out, int L) {
  int tid = threadIdx.x;
  int wv = tid >> 6, lane = tid & 63;
  int arow = lane & 15, kgrp = lane >> 4;
  int mt = blockIdx.x * 4 + wv;  // < 4L
  half8 a[16];
  const _Float16* abase = hcat + (size_t)(mt * 16 + arow) * 512 + kgrp * 8;
#pragma unroll
  for (int kt = 0; kt < 16; ++kt) a[kt] = *(const half8*)(abase + kt * 32);
#pragma unroll
  for (int nt = 0; nt < 5; ++nt) {
    f32x4 acc = {0.f, 0.f, 0.f, 0.f};
    const half8* Bp = (const half8*)(linWp + (size_t)nt * 16 * 512) + lane;
#pragma unroll
    for (int kt = 0; kt < 16; ++kt)
      acc = __builtin_amdgcn_mfma_f32_16x16x32_f16(a[kt], Bp[kt * 64], acc, 0, 0, 0);
    int col = nt * 16 + arow;
    float bb = lin_b[col];
#pragma unroll
    for (int i = 0; i < 4; ++i)
      out[(size_t)(mt * 16 + kgrp * 4 + i) * MEL_ + col] = acc[i] + bb;
  }
}

extern "C" void kernel_launch(void* const* d_in, const int* in_sizes, int n_in,
                              void* d_out, int out_size, void* d_ws, size_t ws_size,
                              hipStream_t stream) {
  const int* x = (const int*)d_in[0];
  const float* embed = (const float*)d_in[1];
  const float* dp_w = (const float*)d_in[2];
  const float* dp_b = (const float*)d_in[3];
  const float* wih_f = (const float*)d_in[4];
  const float* whh_f = (const float*)d_in[5];
  const float* bih_f = (const float*)d_in[6];
  const float* bhh_f = (const float*)d_in[7];
  const float* wih_b = (const float*)d_in[8];
  const float* whh_b = (const float*)d_in[9];
  const float* bih_b = (const float*)d_in[10];
  const float* bhh_b = (const float*)d_in[11];
  const float* lin_w = (const float*)d_in[12];
  const float* lin_b = (const float*)d_in[13];
  float* out = (float*)d_out;
  (void)in_sizes; (void)n_in; (void)ws_size;

  int L = out_size / (B_ * MEL_);
  char* base = (char*)d_ws;
  size_t o = 0;
  auto take = [&](size_t bytes) {
    void* p = base + o;
    o = (o + bytes + 255) & ~(size_t)255;
    return p;
  };
  int* dur = (int*)take((size_t)B_ * T_ * 4);
  int* cum = (int*)take((size_t)B_ * T_ * 4);
  int* idx = (int*)take((size_t)B_ * L * 4);
  _Float16* Wall = (_Float16*)take((size_t)8 * 16 * 12 * 512 * 2);
  float* bsum = (float*)take(2048 * 4);
  _Float16* linWp = (_Float16*)take((size_t)5 * 16 * 512 * 2);
  _Float16* expb = (_Float16*)take((size_t)B_ * L * EMB_ * 2);
  _Float16* hcat = (_Float16*)take((size_t)B_ * L * 512 * 2);

  hipLaunchKernelGGL(k_pack_wall, dim3(384), dim3(256), 0, stream, wih_f, whh_f, wih_b, whh_b, Wall);
  hipLaunchKernelGGL(k_pack_misc, dim3(28), dim3(256), 0, stream, bih_f, bhh_f, bih_b, bhh_b,
                     lin_w, bsum, linWp);
  hipLaunchKernelGGL(k_dur, dim3(128), dim3(256), 0, stream, x, embed, dp_w, dp_b, dur);
  hipLaunchKernelGGL(k_scan, dim3(64), dim3(512), 0, stream, dur, cum);
  hipLaunchKernelGGL(k_fill, dim3((B_ * L + 255) / 256), dim3(256), 0, stream, idx, B_ * L, -1);
  {
    int n4 = B_ * L * 64;  // hcat u32 count / 4
    hipLaunchKernelGGL(k_fill_sent, dim3((n4 + 255) / 256), dim3(256), 0, stream,
                       (unsigned int*)hcat, n4);
  }
  hipLaunchKernelGGL(k_scatter, dim3(64), dim3(512), 0, stream, cum, idx, L);
  hipLaunchKernelGGL(k_expand, dim3((B_ * L * 16 + 255) / 256), dim3(256), 0, stream,
                     x, embed, idx, expb, L);
  hipLaunchKernelGGL(k_rec, dim3(8), dim3(256), 0, stream, expb, Wall, bsum, hcat, L);
  hipLaunchKernelGGL(k_linear, dim3(L), dim3(256), 0, stream, hcat, linWp, lin_b, out, L);
}

// Round 4
// 4972.756 us; speedup vs baseline: 1.3402x; 1.3402x over previous
//
#include <hip/hip_runtime.h>
#include <hip/hip_fp16.h>

#define B_ 64
#define T_ 512
#define EMB_ 128
#define HID_ 256
#define MEL_ 80

typedef __attribute__((ext_vector_type(8))) _Float16 half8;
typedef __attribute__((ext_vector_type(4))) float f32x4;
typedef __attribute__((ext_vector_type(4))) unsigned int u32x4;

__device__ __forceinline__ float sigf(float x) {
  x = fminf(fmaxf(x, -30.f), 30.f);
  return 1.f / (1.f + __expf(-x));
}
__device__ __forceinline__ float tanhf_(float x) {
  x = fminf(fmaxf(x, -15.f), 15.f);
  float e = __expf(2.f * x);
  return (e - 1.f) / (e + 1.f);
}

// Barrier that drains ONLY LDS (lgkmcnt), not vmcnt: publish stores and poll
// loads stay in flight across it. All cross-wave data handoff here is LDS.
__device__ __forceinline__ void barrier_lds() {
  __builtin_amdgcn_sched_barrier(0);
  asm volatile("s_waitcnt lgkmcnt(0)" ::: "memory");
  __builtin_amdgcn_s_barrier();
  __builtin_amdgcn_sched_barrier(0);
}

// Pack W=[wih|whh] (per dir 1024x384) into MFMA B-frags with PER-BLOCK K order:
// [ x(0..127) | own-slice h(64) | remote slices in ascending-slice order (192) ].
// Rows permuted to gu-order (wave wv owns units wv*16.., gates via nt=wv+4g).
// Wall[((ds*16+nt)*12+kt)*64 + lane][8]
__global__ void k_pack_wall(const float* __restrict__ wih_f, const float* __restrict__ whh_f,
                            const float* __restrict__ wih_b, const float* __restrict__ whh_b,
                            _Float16* __restrict__ Wall) {
  int tid = blockIdx.x * 256 + threadIdx.x;  // 98304 total
  int lane = tid & 63;
  int r = tid >> 6;
  int kt = r % 12; r /= 12;
  int nt = r % 16; r /= 16;
  int ds = r;  // 0..7
  if (ds >= 8) return;
  int dir = ds >> 2, slice = ds & 3;
  const float* wih = dir ? wih_b : wih_f;
  const float* whh = dir ? whh_b : whh_f;
  int gu = nt * 16 + (lane & 15);
  int g = gu >> 6, u = gu & 63;
  int row = g * 256 + slice * 64 + u;
  int kbase = kt * 32 + (lane >> 4) * 8;
  _Float16* dst = Wall + (size_t)tid * 8;
#pragma unroll
  for (int j = 0; j < 8; ++j) {
    int k = kbase + j;
    float v;
    if (k < EMB_) {
      v = wih[row * EMB_ + k];
    } else if (k < EMB_ + 64) {
      v = whh[row * HID_ + slice * 64 + (k - EMB_)];
    } else {
      int jx = k - (EMB_ + 64);
      int rr = jx >> 6;
      int ps = rr + (rr >= slice ? 1 : 0);
      v = whh[row * HID_ + ps * 64 + (jx & 63)];
    }
    dst[j] = (_Float16)v;
  }
}

__global__ void k_pack_misc(const float* __restrict__ bih_f, const float* __restrict__ bhh_f,
                            const float* __restrict__ bih_b, const float* __restrict__ bhh_b,
                            const float* __restrict__ lin_w, float* __restrict__ bsum,
                            _Float16* __restrict__ linWp) {
  int t = blockIdx.x * 256 + threadIdx.x;
  if (t < 2048) {
    int dir = t >> 10, g = t & 1023;
    bsum[t] = dir ? (bih_b[g] + bhh_b[g]) : (bih_f[g] + bhh_f[g]);
  } else if (t < 2048 + 5120) {
    int u = t - 2048;
    int lane = u & 63;
    int r = u >> 6;
    int kt = r % 16, nt = r / 16;
    int n = nt * 16 + (lane & 15);
    int kbase = kt * 32 + (lane >> 4) * 8;
    _Float16* dst = linWp + (size_t)u * 8;
#pragma unroll
    for (int j = 0; j < 8; ++j) dst[j] = (_Float16)lin_w[n * 512 + kbase + j];
  }
}

__global__ void k_dur(const int* __restrict__ x, const float* __restrict__ embed,
                      const float* __restrict__ dp_w, const float* __restrict__ dp_b,
                      int* __restrict__ dur) {
  int gid = blockIdx.x * 256 + threadIdx.x;
  if (gid >= B_ * T_) return;
  const float* er = embed + (size_t)x[gid] * EMB_;
  float d = 0.f;
  for (int e = 0; e < EMB_; ++e) d += er[e] * dp_w[e];
  d += dp_b[0];
  d = fmaxf(d, 0.f);
  dur[gid] = (int)floorf(d) + 1;
}

__global__ void k_scan(const int* __restrict__ dur, int* __restrict__ cum) {
  __shared__ int s[512];
  int b = blockIdx.x, t = threadIdx.x;
  s[t] = dur[b * 512 + t];
  __syncthreads();
  for (int off = 1; off < 512; off <<= 1) {
    int v = (t >= off) ? s[t - off] : 0;
    __syncthreads();
    s[t] += v;
    __syncthreads();
  }
  cum[b * 512 + t] = s[t];
}

__global__ void k_fill(int* __restrict__ p, int n, int v) {
  int gid = blockIdx.x * 256 + threadIdx.x;
  if (gid < n) p[gid] = v;
}

// sentinel-fill mailbox (0xFFFFFFFF = fp16 NaN pair, impossible as real h)
__global__ void k_fill_sent(unsigned int* __restrict__ p, int n4) {
  int gid = blockIdx.x * 256 + threadIdx.x;
  if (gid < n4) ((u32x4*)p)[gid] = u32x4{0xFFFFFFFFu, 0xFFFFFFFFu, 0xFFFFFFFFu, 0xFFFFFFFFu};
}

__global__ void k_scatter(const int* __restrict__ cum, int* __restrict__ idx, int L) {
  int b = blockIdx.x, t = threadIdx.x;
  int c1 = cum[b * 512 + t];
  int c0 = t ? cum[b * 512 + t - 1] : 0;
  for (int p = c0; p < c1; ++p)
    if (p < L) idx[(size_t)b * L + p] = t;
}

__global__ void k_expand(const int* __restrict__ x, const float* __restrict__ embed,
                         const int* __restrict__ idx, _Float16* __restrict__ expb, int L) {
  int gid = blockIdx.x * 256 + threadIdx.x;
  if (gid >= B_ * L * 16) return;
  int ch = gid & 15;
  int rem = gid >> 4;
  int l = rem % L;
  int b = rem / L;
  int ix = idx[(size_t)b * L + l];
  half8 v;
  if (ix < 0) {
#pragma unroll
    for (int j = 0; j < 8; ++j) v[j] = (_Float16)0.f;
  } else {
    const float* er = embed + (size_t)x[b * 512 + ix] * EMB_ + ch * 8;
#pragma unroll
    for (int j = 0; j < 8; ++j) v[j] = (_Float16)er[j];
  }
  *(half8*)(expb + ((size_t)b * L + l) * EMB_ + ch * 8) = v;
}

// 8 blocks = 2 dirs x 4 hidden-slices. Weights resident in regs.
// Mailbox (batch-major [l][dir][b][u], u16) holds h for exchange + k_linear.
// Producers: pair-packed relaxed u32 agent stores (fire-and-forget: barriers
// drain lgkm only). Consumers: 24 wave-coalesced relaxed u32 loads, retry
// words still sentinel. GEMM-A (x+own h) overlaps the poll flight.
__global__ __launch_bounds__(256, 1) void k_rec(
    const _Float16* __restrict__ expb, const _Float16* __restrict__ Wall,
    const float* __restrict__ bsum, _Float16* __restrict__ mail, int L) {
  __shared__ __align__(16) _Float16 Ash[64][392];  // [b][ x(128) | own(64) | remote(192) | pad ]
  int tid = threadIdx.x;
  int ds = blockIdx.x;
  int dir = ds >> 2, slice = ds & 3;
  int wv = tid >> 6, lane = tid & 63;
  int c = lane & 15, kg = lane >> 4;
  unsigned int* mail32 = (unsigned int*)mail;
  int cb = tid >> 2, q = tid & 3;  // consumer: batch cb, word-lane q
  int s32 = slice * 32;

  for (int i = tid; i < 64 * 392 / 8; i += 256)
    ((half8*)&Ash[0][0])[i] = half8{0, 0, 0, 0, 0, 0, 0, 0};
  float bias[4];
#pragma unroll
  for (int g = 0; g < 4; ++g)
    bias[g] = bsum[dir * 1024 + g * 256 + slice * 64 + wv * 16 + c];
  half8 breg[4][12];
#pragma unroll
  for (int g = 0; g < 4; ++g) {
    int nt = wv + 4 * g;
#pragma unroll
    for (int kt = 0; kt < 12; ++kt)
      breg[g][kt] = *(const half8*)(Wall + (((size_t)(ds * 16 + nt) * 12 + kt) * 64 + lane) * 8);
  }
  float creg[16];
#pragma unroll
  for (int i = 0; i < 16; ++i) creg[i] = 0.f;
  __syncthreads();
  {  // x_0
    int l0 = dir ? (L - 1) : 0;
#pragma unroll
    for (int r = 0; r < 4; ++r) {
      int f = tid + 256 * r;
      int b = f >> 4, ch = f & 15;
      *(half8*)&Ash[b][ch * 8] = *(const half8*)(expb + ((size_t)b * L + l0) * EMB_ + ch * 8);
    }
  }
  __syncthreads();

  for (int s = 0; s < L; ++s) {
    int l_io = dir ? (L - 1 - s) : s;
    // --- p0: issue coalesced poll loads for remote h_{s-1} + x(s+1) prefetch ---
    unsigned int v[24];
    const unsigned int* rp = nullptr;
    if (s > 0) {
      int l_prev = dir ? (L - s) : (s - 1);
      rp = mail32 + ((size_t)(l_prev * 2 + dir) * 64 + cb) * 128;
#pragma unroll
      for (int wd = 0; wd < 24; ++wd) {
        int j32 = wd * 4 + q;
        int jm = j32 + (j32 >= s32 ? 32 : 0);
        v[wd] = __hip_atomic_load(rp + jm, __ATOMIC_RELAXED, __HIP_MEMORY_SCOPE_AGENT);
      }
    }
    half8 xr[4];
    if (s + 1 < L) {
      int l1 = dir ? (L - 2 - s) : (s + 1);
#pragma unroll
      for (int r = 0; r < 4; ++r) {
        int f = tid + 256 * r;
        int b = f >> 4, ch = f & 15;
        xr[r] = *(const half8*)(expb + ((size_t)b * L + l1) * EMB_ + ch * 8);
      }
    }
    // --- p1: GEMM-A (x_s + own h_{s-1}), overlaps poll flight ---
    f32x4 acc[4][4];
#pragma unroll
    for (int m = 0; m < 4; ++m)
#pragma unroll
      for (int g = 0; g < 4; ++g) acc[m][g] = f32x4{0.f, 0.f, 0.f, 0.f};
#pragma unroll
    for (int kt = 0; kt < 6; ++kt) {
      half8 a[4];
#pragma unroll
      for (int m = 0; m < 4; ++m) a[m] = *(const half8*)&Ash[m * 16 + c][kt * 32 + kg * 8];
#pragma unroll
      for (int m = 0; m < 4; ++m)
#pragma unroll
        for (int g = 0; g < 4; ++g)
          acc[m][g] = __builtin_amdgcn_mfma_f32_16x16x32_f16(a[m], breg[g][kt], acc[m][g], 0, 0, 0);
    }
    // --- p2: validate polls; remote h -> Ash (2-way-bank-free scalar writes) ---
    if (s > 0) {
      while (true) {
        int miss = 0;
#pragma unroll
        for (int wd = 0; wd < 24; ++wd) miss |= (v[wd] == 0xFFFFFFFFu) ? 1 : 0;
        if (!__any(miss)) break;
        __builtin_amdgcn_s_sleep(2);
#pragma unroll
        for (int wd = 0; wd < 24; ++wd)
          if (v[wd] == 0xFFFFFFFFu) {
            int j32 = wd * 4 + q;
            int jm = j32 + (j32 >= s32 ? 32 : 0);
            v[wd] = __hip_atomic_load(rp + jm, __ATOMIC_RELAXED, __HIP_MEMORY_SCOPE_AGENT);
          }
      }
      unsigned int* ar = (unsigned int*)&Ash[cb][0];
#pragma unroll
      for (int wd = 0; wd < 24; ++wd) ar[96 + wd * 4 + q] = v[wd];
    }
    barrier_lds();  // B1
    // --- p3: x(s+1) -> Ash (region free after GEMM-A) ---
    if (s + 1 < L) {
#pragma unroll
      for (int r = 0; r < 4; ++r) {
        int f = tid + 256 * r;
        int b = f >> 4, ch = f & 15;
        *(half8*)&Ash[b][ch * 8] = xr[r];
      }
    }
    // --- p4: GEMM-B (remote h) ---
#pragma unroll
    for (int kt = 6; kt < 12; ++kt) {
      half8 a[4];
#pragma unroll
      for (int m = 0; m < 4; ++m) a[m] = *(const half8*)&Ash[m * 16 + c][kt * 32 + kg * 8];
#pragma unroll
      for (int m = 0; m < 4; ++m)
#pragma unroll
        for (int g = 0; g < 4; ++g)
          acc[m][g] = __builtin_amdgcn_mfma_f32_16x16x32_f16(a[m], breg[g][kt], acc[m][g], 0, 0, 0);
    }
    // --- p5: cell update ---
    _Float16 hv[16];
#pragma unroll
    for (int m = 0; m < 4; ++m)
#pragma unroll
      for (int i = 0; i < 4; ++i) {
        float iv = acc[m][0][i] + bias[0];
        float fv = acc[m][1][i] + bias[1];
        float gv = acc[m][2][i] + bias[2];
        float ov = acc[m][3][i] + bias[3];
        float cc = sigf(fv) * creg[m * 4 + i] + sigf(iv) * tanhf_(gv);
        float hh = sigf(ov) * tanhf_(cc);
        creg[m * 4 + i] = cc;
        hv[m * 4 + i] = (_Float16)hh;
      }
    // --- p6: publish h_s (pair-packed u32, relaxed agent, never drained) ---
#pragma unroll
    for (int m = 0; m < 4; ++m)
#pragma unroll
      for (int i = 0; i < 4; ++i) {
        int id = m * 4 + i;
        unsigned int mine = (unsigned int)__builtin_bit_cast(unsigned short, hv[id]);
        unsigned int part = (unsigned int)(unsigned)__shfl_xor((int)mine, 1, 64);
        unsigned int word = (c & 1) ? ((mine << 16) | part) : (mine | (part << 16));
        if (((c & 1) == 0) == (m < 2)) {
          int b = m * 16 + kg * 4 + i;
          __hip_atomic_store(
              mail32 + ((size_t)(l_io * 2 + dir) * 64 + b) * 128 + slice * 32 + wv * 8 + (c >> 1),
              word, __ATOMIC_RELAXED, __HIP_MEMORY_SCOPE_AGENT);
        }
      }
    // --- p7: own h -> Ash ---
#pragma unroll
    for (int m = 0; m < 4; ++m)
#pragma unroll
      for (int i = 0; i < 4; ++i)
        Ash[m * 16 + kg * 4 + i][EMB_ + wv * 16 + c] = hv[m * 4 + i];
    barrier_lds();  // B2
  }
}

// out[r,:80] = h(b,l) @ lin_w.T + lin_b, reading from mailbox [l][dir][b][u]
__global__ __launch_bounds__(256) void k_linear(
    const _Float16* __restrict__ mail, const _Float16* __restrict__ linWp,
    const float* __restrict__ lin_b, float* __restrict__ out, int L) {
  int tid = threadIdx.x;
  int wv = tid >> 6, lane = tid & 63;
  int arow = lane & 15, kgrp = lane >> 4;
  int mt = blockIdx.x * 4 + wv;  // < 4L
  int r0 = mt * 16 + arow;       // A-row = b*L + l
  int b = r0 / L, l = r0 - b * L;
  const _Float16* base0 = mail + ((size_t)(l * 2 + 0) * 64 + b) * 256 + kgrp * 8;
  const _Float16* base1 = mail + ((size_t)(l * 2 + 1) * 64 + b) * 256 + kgrp * 8;
  half8 a[16];
#pragma unroll
  for (int kt = 0; kt < 8; ++kt) a[kt] = *(const half8*)(base0 + kt * 32);
#pragma unroll
  for (int kt = 8; kt < 16; ++kt) a[kt] = *(const half8*)(base1 + (kt - 8) * 32);
#pragma unroll
  for (int nt = 0; nt < 5; ++nt) {
    f32x4 acc = {0.f, 0.f, 0.f, 0.f};
    const half8* Bp = (const half8*)(linWp + (size_t)nt * 16 * 512) + lane;
#pragma unroll
    for (int kt = 0; kt < 16; ++kt)
      acc = __builtin_amdgcn_mfma_f32_16x16x32_f16(a[kt], Bp[kt * 64], acc, 0, 0, 0);
    int col = nt * 16 + arow;
    float bb = lin_b[col];
#pragma unroll
    for (int i = 0; i < 4; ++i)
      out[(size_t)(mt * 16 + kgrp * 4 + i) * MEL_ + col] = acc[i] + bb;
  }
}

extern "C" void kernel_launch(void* const* d_in, const int* in_sizes, int n_in,
                              void* d_out, int out_size, void* d_ws, size_t ws_size,
                              hipStream_t stream) {
  const int* x = (const int*)d_in[0];
  const float* embed = (const float*)d_in[1];
  const float* dp_w = (const float*)d_in[2];
  const float* dp_b = (const float*)d_in[3];
  const float* wih_f = (const float*)d_in[4];
  const float* whh_f = (const float*)d_in[5];
  const float* bih_f = (const float*)d_in[6];
  const float* bhh_f = (const float*)d_in[7];
  const float* wih_b = (const float*)d_in[8];
  const float* whh_b = (const float*)d_in[9];
  const float* bih_b = (const float*)d_in[10];
  const float* bhh_b = (const float*)d_in[11];
  const float* lin_w = (const float*)d_in[12];
  const float* lin_b = (const float*)d_in[13];
  float* out = (float*)d_out;
  (void)in_sizes; (void)n_in; (void)ws_size;

  int L = out_size / (B_ * MEL_);
  char* base = (char*)d_ws;
  size_t o = 0;
  auto take = [&](size_t bytes) {
    void* p = base + o;
    o = (o + bytes + 255) & ~(size_t)255;
    return p;
  };
  int* dur = (int*)take((size_t)B_ * T_ * 4);
  int* cum = (int*)take((size_t)B_ * T_ * 4);
  int* idx = (int*)take((size_t)B_ * L * 4);
  _Float16* Wall = (_Float16*)take((size_t)8 * 16 * 12 * 512 * 2);
  float* bsum = (float*)take(2048 * 4);
  _Float16* linWp = (_Float16*)take((size_t)5 * 16 * 512 * 2);
  _Float16* expb = (_Float16*)take((size_t)B_ * L * EMB_ * 2);
  _Float16* mail = (_Float16*)take((size_t)L * 2 * 64 * 256 * 2);

  hipLaunchKernelGGL(k_pack_wall, dim3(384), dim3(256), 0, stream, wih_f, whh_f, wih_b, whh_b, Wall);
  hipLaunchKernelGGL(k_pack_misc, dim3(28), dim3(256), 0, stream, bih_f, bhh_f, bih_b, bhh_b,
                     lin_w, bsum, linWp);
  hipLaunchKernelGGL(k_dur, dim3(128), dim3(256), 0, stream, x, embed, dp_w, dp_b, dur);
  hipLaunchKernelGGL(k_scan, dim3(64), dim3(512), 0, stream, dur, cum);
  hipLaunchKernelGGL(k_fill, dim3((B_ * L + 255) / 256), dim3(256), 0, stream, idx, B_ * L, -1);
  {
    int n4 = L * 4096;  // mailbox u32 count / 4
    hipLaunchKernelGGL(k_fill_sent, dim3((n4 + 255) / 256), dim3(256), 0, stream,
                       (unsigned int*)mail, n4);
  }
  hipLaunchKernelGGL(k_scatter, dim3(64), dim3(512), 0, stream, cum, idx, L);
  hipLaunchKernelGGL(k_expand, dim3((B_ * L * 16 + 255) / 256), dim3(256), 0, stream,
                     x, embed, idx, expb, L);
  hipLaunchKernelGGL(k_rec, dim3(8), dim3(256), 0, stream, expb, Wall, bsum, mail, L);
  hipLaunchKernelGGL(k_linear, dim3(L), dim3(256), 0, stream, mail, linWp, lin_b, out, L);
}